// Round 4
// baseline (107.168 us; speedup 1.0000x reference)
//
#include <hip/hip_runtime.h>
#include <math.h>

// AdderModel: B=16384 rows, T=64 (== wave), D=3, HD=4, FF=2, VOCAB=10.
// Round 14 = r12-validated numerics + r13's value-preserving structure.
// r13 post-mortem: QK^T k-slot packing (3 MFMAs -> 1 per tile) degraded
// absmax 0.031->0.109 (over the 0.0906 threshold) -- the single 12-term
// internal MFMA reduction is numerically worse than 3 chained 4-term MFMAs.
// It was the only value-changing edit in r13 -> reverted here.
// Kept from r13 (no value changes):
//  - idx HBM load issued first; table writes/trig/weights hide under it.
//  - per-wave digit table (96 B/wave), zero block-wide barriers.
//  - r12 coalesced LDS-staged nontemporal stores (validated -7.5 us).
// New in r14 (scheduling only): the 8 Vt ds_writes are hoisted to right
// after v0..v3 (before RoPE/splits/shuffles), so the writes drain under
// ~40 VALU ops and the pre-vb fence is nearly free.
// Numerics identical to r12: hi/lo fp32-accurate scores via 3-term chains,
// cndmask-at-exp causal mask, half-up packs with exact split, register-order
// P + swap23 vcol, per-wave table logits.

namespace {
constexpr int kVocab = 10;
constexpr float kEps = 1e-6f;
constexpr int kWaves = 4;

typedef __attribute__((ext_vector_type(8)))  short short8;
typedef __attribute__((ext_vector_type(16))) float float16;
typedef __attribute__((ext_vector_type(4)))  float floatx4;
typedef __attribute__((ext_vector_type(2)))  float floatx2;

constexpr int kVtP = 72;          // Vt row pitch in shorts (144 B)
constexpr int kWaveLds = 2560;    // max(Vt 8x144 B, logit staging 64x40 B)

// f32 -> bf16, round-half-up (inputs finite; hi/lo split residual is taken
// from the ACTUAL packed hi, so the split stays exact).
__device__ __forceinline__ unsigned bf16_1(float a) {
    return (__float_as_uint(a) + 0x8000u) >> 16;
}
__device__ __forceinline__ unsigned pk_bf16(float a, float b) {
    const unsigned au = __float_as_uint(a) + 0x8000u;
    const unsigned bu = __float_as_uint(b) + 0x8000u;
    return (au >> 16) | (bu & 0xffff0000u);
}
__device__ __forceinline__ float bf_lo(unsigned u) { return __uint_as_float(u << 16); }
__device__ __forceinline__ float bf_hi(unsigned u) { return __uint_as_float(u & 0xffff0000u); }

__device__ __forceinline__ float16 mfma(short8 a, short8 b, float16 c) {
    return __builtin_amdgcn_mfma_f32_32x32x16_bf16(a, b, c, 0, 0, 0);
}
__device__ __forceinline__ unsigned shflx32(unsigned x) {
    return (unsigned)__shfl_xor((int)x, 32, 64);
}

// Frag from a packed bf16x4: k-slots 0..3 hold {x0..x3} on lanes<32 (k=0..7
// half), zeros on lanes>=32 (k=8..15 half).  [r8/r9-validated form]
__device__ __forceinline__ short8 mk_frag(uint2 v, bool lo) {
    uint4 t;
    t.x = lo ? v.x : 0u;
    t.y = lo ? v.y : 0u;
    t.z = 0u; t.w = 0u;
    return __builtin_bit_cast(short8, t);
}
__device__ __forceinline__ short8 ld8(const void* p) {
    return __builtin_bit_cast(short8, *(const uint4*)p);
}

// exp2 + pack a score tile IN REGISTER ORDER: out[i] = pk(e[2i], e[2i+1]).
// Causal mask (validated): reg r has s_local = (r&3)+8*(r>>2)+4h, keep iff
// ((r&3)+8*(r>>2)) <= m where m = tloc-4h.
template<bool MASKED>
__device__ __forceinline__ void exp_pack(const float16& S, unsigned* out, int m) {
#pragma unroll
    for (int i = 0; i < 8; ++i) {
        const int r0 = 2 * i, r1 = 2 * i + 1;
        float sa = S[r0], sb = S[r1];
        if (MASKED) {
            sa = (((r0 & 3) + 8 * (r0 >> 2)) <= m) ? sa : -INFINITY;  // exp2 -> 0
            sb = (((r1 & 3) + 8 * (r1 >> 2)) <= m) ? sb : -INFINITY;
        }
        out[i] = pk_bf16(__builtin_amdgcn_exp2f(sa), __builtin_amdgcn_exp2f(sb));
    }
}

// Operand chunk straight from 4 packed uints (8 bf16).
__device__ __forceinline__ short8 af(const unsigned* p) {
    uint4 t;
    t.x = p[0]; t.y = p[1]; t.z = p[2]; t.w = p[3];
    return __builtin_bit_cast(short8, t);
}

__global__ __launch_bounds__(256, 4) void adder_model_kernel(
    const int* __restrict__ idx,
    const float* __restrict__ p_arcA,
    const float* __restrict__ p_arcStart,
    const float* __restrict__ p_arcStride,
    const float* __restrict__ w_ln1,
    const float* __restrict__ w_ln2,
    const float* __restrict__ w_lnf,
    const float* __restrict__ w_qn,
    const float* __restrict__ Wq,
    const float* __restrict__ Wk,
    const float* __restrict__ Wg,
    const float* __restrict__ Wu,
    const float* __restrict__ Wd,
    float* __restrict__ out)
{
    __shared__ __align__(16) char smem[kWaves][kWaveLds];
    __shared__ __align__(16) float tw[kWaves][24];   // per-wave digit table

    const int lane = threadIdx.x & 63;
    const int wid  = threadIdx.x >> 6;
    ushort* Vt = (ushort*)&smem[wid][0];

    const int row = (int)blockIdx.x * kWaves + wid;

    // Longest-latency item first: idx HBM read (~900 cy). Everything below
    // (table writes, trig constants, scalar weight loads) hides under it.
    const int tix = idx[(size_t)row * 64 + lane];

    // Per-wave digit table: lanes 0-9 write a private 96 B copy; wave-local
    // LDS ordering needs only the fence below (no block barrier anywhere).
    if (lane < kVocab) {
        const float ang = p_arcStart[0] + (float)lane * p_arcStride[0];
        const float A = p_arcA[0];
        tw[wid][2 * lane]     = A * __cosf(ang);
        tw[wid][2 * lane + 1] = A * __sinf(ang);
    }

    // Per-token constants
    const float t_f = (float)lane;
    const float pe  = __sinf(t_f * 1e-4f);
    const float c0  = __cosf(t_f);
    const float s0  = __sinf(t_f);
    const float ang1 = t_f * 0.57735026918962576f;
    const float c1  = __cosf(ang1);
    const float s1  = __sinf(ang1);

    // Scalar weight loads (uniform -> SGPR)
    const float wl1_0 = w_ln1[0], wl1_1 = w_ln1[1], wl1_2 = w_ln1[2];
    const float wl2_0 = w_ln2[0], wl2_1 = w_ln2[1], wl2_2 = w_ln2[2];
    const float wlf0 = w_lnf[0], wlf1 = w_lnf[1];
    const float wqn0 = w_qn[0], wqn1 = w_qn[1], wqn2 = w_qn[2], wqn3 = w_qn[3];
    const float Wq00 = Wq[0],  Wq01 = Wq[1],  Wq02 = Wq[2];
    const float Wq10 = Wq[3],  Wq11 = Wq[4],  Wq12 = Wq[5];
    const float Wq20 = Wq[6],  Wq21 = Wq[7],  Wq22 = Wq[8];
    const float Wq30 = Wq[9],  Wq31 = Wq[10], Wq32 = Wq[11];
    const float Wk00 = Wk[0],  Wk01 = Wk[1],  Wk02 = Wk[2];
    const float Wk10 = Wk[3],  Wk11 = Wk[4],  Wk12 = Wk[5];
    const float Wk20 = Wk[6],  Wk21 = Wk[7],  Wk22 = Wk[8];
    const float Wk30 = Wk[9],  Wk31 = Wk[10], Wk32 = Wk[11];
    const float Wg00 = Wg[0],  Wg01 = Wg[1],  Wg02 = Wg[2];
    const float Wg10 = Wg[3],  Wg11 = Wg[4],  Wg12 = Wg[5];
    const float Wu00 = Wu[0],  Wu01 = Wu[1],  Wu02 = Wu[2];
    const float Wu10 = Wu[3],  Wu11 = Wu[4],  Wu12 = Wu[5];
    const float Wd00 = Wd[0],  Wd01 = Wd[1];
    const float Wd10 = Wd[2],  Wd11 = Wd[3];
    const float Wd20 = Wd[4],  Wd21 = Wd[5];

    __threadfence_block();  // table writes -> cross-lane emb reads (same wave)

    const float2 emb = *(const float2*)(&tw[wid][2 * tix]);
    const float x0i = emb.x, x1i = emb.y, x2i = pe;

    // RMSNorm 1 + projections
    const float r1 = __builtin_amdgcn_rsqf((x0i*x0i + x1i*x1i + x2i*x2i) * (1.0f/3.0f) + kEps);
    const float h0 = x0i * r1 * wl1_0;
    const float h1 = x1i * r1 * wl1_1;
    const float h2 = x2i * r1 * wl1_2;

    const float qp0 = h0*Wq00 + h1*Wq01 + h2*Wq02;
    const float qp1 = h0*Wq10 + h1*Wq11 + h2*Wq12;
    const float qp2 = h0*Wq20 + h1*Wq21 + h2*Wq22;
    const float qp3 = h0*Wq30 + h1*Wq31 + h2*Wq32;
    const float v0 = h0*Wk00 + h1*Wk01 + h2*Wk02;
    const float v1 = h0*Wk10 + h1*Wk11 + h2*Wk12;
    const float v2 = h0*Wk20 + h1*Wk21 + h2*Wk22;
    const float v3 = h0*Wk30 + h1*Wk31 + h2*Wk32;

    // Vt writes HOISTED here (scheduling only): they drain under the
    // RoPE/split/shuffle VALU stretch below, making the pre-vb fence cheap.
    // V' rows (d=0..3, ones row d=4, zero pad rows 5..7) at swap23 columns:
    // vcol(s) = swap(bit2,bit3)(s) matches the register k->s mapping
    // [0,1,2,3,8,9,10,11 | 4,5,6,7,12,13,14,15] per 16-chunk. [r9-validated]
    const int vcol = (lane & ~12) | ((lane & 4) << 1) | ((lane & 8) >> 1);
    Vt[0 * kVtP + vcol] = (ushort)bf16_1(v0);
    Vt[1 * kVtP + vcol] = (ushort)bf16_1(v1);
    Vt[2 * kVtP + vcol] = (ushort)bf16_1(v2);
    Vt[3 * kVtP + vcol] = (ushort)bf16_1(v3);
    Vt[4 * kVtP + vcol] = (ushort)0x3F80;  // bf16 1.0 -> l = sum_s P[t][s]
    Vt[5 * kVtP + vcol] = 0;               // defined junk for A pad rows
    Vt[6 * kVtP + vcol] = 0;
    Vt[7 * kVtP + vcol] = 0;

    const float rq = __builtin_amdgcn_rsqf((qp0*qp0 + qp1*qp1 + qp2*qp2 + qp3*qp3) * 0.25f + kEps);
    const float rk = __builtin_amdgcn_rsqf((v0*v0 + v1*v1 + v2*v2 + v3*v3) * 0.25f + kEps);
    const float qn0 = qp0*rq*wqn0, qn1 = qp1*rq*wqn1, qn2 = qp2*rq*wqn2, qn3 = qp3*rq*wqn3;
    const float kn0 = v0*rk*wqn0,  kn1 = v1*rk*wqn1,  kn2 = v2*rk*wqn2,  kn3 = v3*rk*wqn3;

    // RoPE; fold 0.5*log2(e) into q -> scores land in exp2 domain
    constexpr float kQS = 0.72134752044448170f;
    const float q0 = (qn0*c0 - qn1*s0) * kQS;
    const float q1 = (qn0*s0 + qn1*c0) * kQS;
    const float q2 = (qn2*c1 - qn3*s1) * kQS;
    const float q3 = (qn2*s1 + qn3*c1) * kQS;
    const float k0 = kn0*c0 - kn1*s0;
    const float k1 = kn0*s0 + kn1*c0;
    const float k2 = kn2*c1 - kn3*s1;
    const float k3 = kn2*s1 + kn3*c1;

    // hi/lo bf16 split (residual from the ACTUAL packed hi -> exact split)
    uint2 qh, ql, kh, kl;
    qh.x = pk_bf16(q0, q1); qh.y = pk_bf16(q2, q3);
    ql.x = pk_bf16(q0 - bf_lo(qh.x), q1 - bf_hi(qh.x));
    ql.y = pk_bf16(q2 - bf_lo(qh.y), q3 - bf_hi(qh.y));
    kh.x = pk_bf16(k0, k1); kh.y = pk_bf16(k2, k3);
    kl.x = pk_bf16(k0 - bf_lo(kh.x), k1 - bf_hi(kh.x));
    kl.y = pk_bf16(k2 - bf_lo(kh.y), k3 - bf_hi(kh.y));

    // Tile-1 values: partner half's qh/ql/kh/kl via half-swap (no LDS buffer)
    uint2 qh1, ql1, kh1, kl1;
    qh1.x = shflx32(qh.x); qh1.y = shflx32(qh.y);
    ql1.x = shflx32(ql.x); ql1.y = shflx32(ql.y);
    kh1.x = shflx32(kh.x); kh1.y = shflx32(kh.y);
    kl1.x = shflx32(kl.x); kl1.y = shflx32(kl.y);

    const int  tloc = lane & 31;
    const bool loh  = lane < 32;
    const int  h    = lane >> 5;
    const int  m    = tloc - 4 * h;   // causal keep: s_local <= m

    // Fragments: tile-0 from own registers (lane<32 token == own lane;
    // lane>=32 zeroed by the select anyway). Tile-1 from the half-swap.
    const short8 aKh0 = mk_frag(kh,  loh);
    const short8 aKl0 = mk_frag(kl,  loh);
    const short8 aKh1 = mk_frag(kh1, loh);
    const short8 aKl1 = mk_frag(kl1, loh);
    const short8 bQh0 = mk_frag(qh,  loh);
    const short8 bQl0 = mk_frag(ql,  loh);
    const short8 bQh1 = mk_frag(qh1, loh);
    const short8 bQl1 = mk_frag(ql1, loh);

    __threadfence_block();  // Vt writes -> cross-lane vb reads (writes long drained)

    // V' operand chunks (row d = tloc, pad-masked to 8 rows) [r9 read pattern]
    short8 vb[4];
#pragma unroll
    for (int kc = 0; kc < 4; ++kc)
        vb[kc] = ld8(Vt + (tloc & 7) * kVtP + 16 * kc + 8 * h);

    // S^T tiles = K.Q^T; 3-term hi/lo product (drop lo*lo ~2^-18)
    // [r12-validated numerics -- do NOT fuse into k-slot-packed MFMAs;
    //  r13 measured absmax 0.031 -> 0.109 from that fusion]
    float16 Z = {0,0,0,0,0,0,0,0,0,0,0,0,0,0,0,0};
    float16 S00 = mfma(aKl0, bQh0, mfma(aKh0, bQl0, mfma(aKh0, bQh0, Z)));
    float16 S01 = mfma(aKl0, bQh1, mfma(aKh0, bQl1, mfma(aKh0, bQh1, Z)));
    float16 S11 = mfma(aKl1, bQh1, mfma(aKh1, bQl1, mfma(aKh1, bQh1, Z)));

    // exp2 + pack in register order; packed regs ARE the PV B-operand.
    unsigned p00[8], p01[8], p11[8];
    exp_pack<true >(S00, p00, m);  // t<32,  s<32: diag mask
    exp_pack<false>(S01, p01, m);  // t>=32, s<32: fully kept
    exp_pack<true >(S11, p11, m);  // t>=32, s>=32: diag mask

    // O' = V'.P : A = vb (m=d), B = packed P (n=t) -> D[d][t] token-per-lane.
    float16 acc0 = mfma(vb[1], af(p00 + 4), mfma(vb[0], af(p00), Z));
    float16 acc1 = mfma(vb[3], af(p11 + 4),
                   mfma(vb[2], af(p11),
                   mfma(vb[1], af(p01 + 4),
                   mfma(vb[0], af(p01), Z))));

    // Redistribute via half-swap: lane(tloc,h=0) holds o0..3(tloc)=acc0[0..3]
    // and o0..3(tloc+32)=acc1[0..3]; lane(tloc,h=1) holds l(tloc)=acc0[0]
    // (m=4 -> r=0) and l(tloc+32)=acc1[0].
    const float e0 = __shfl_xor(loh ? acc1[0] : acc0[0], 32, 64);
    const float e1 = __shfl_xor(loh ? acc1[1] : acc0[1], 32, 64);
    const float e2 = __shfl_xor(loh ? acc1[2] : acc0[2], 32, 64);
    const float e3 = __shfl_xor(loh ? acc1[3] : acc0[3], 32, 64);
    const float o0r = loh ? acc0[0] : e0;
    const float o1r = loh ? acc0[1] : e1;
    const float o2r = loh ? acc0[2] : e2;
    const float o3r = loh ? acc0[3] : e3;
    const float lr  = loh ? e0 : acc1[0];

    const float invl = __builtin_amdgcn_rcpf(lr);
    const float o0 = o0r * invl, o1 = o1r * invl, o2 = o2r * invl, o3 = o3r * invl;

    // x += o @ Wq
    const float xa0 = x0i + o0*Wq00 + o1*Wq10 + o2*Wq20 + o3*Wq30;
    const float xa1 = x1i + o0*Wq01 + o1*Wq11 + o2*Wq21 + o3*Wq31;
    const float xa2 = x2i + o0*Wq02 + o1*Wq12 + o2*Wq22 + o3*Wq32;

    // MLP with RMSNorm 2
    const float r2 = __builtin_amdgcn_rsqf((xa0*xa0 + xa1*xa1 + xa2*xa2) * (1.0f/3.0f) + kEps);
    const float hh0 = xa0*r2*wl2_0, hh1 = xa1*r2*wl2_1, hh2 = xa2*r2*wl2_2;
    const float g0 = hh0*Wg00 + hh1*Wg01 + hh2*Wg02;
    const float g1 = hh0*Wg10 + hh1*Wg11 + hh2*Wg12;
    const float u0 = hh0*Wu00 + hh1*Wu01 + hh2*Wu02;
    const float u1 = hh0*Wu10 + hh1*Wu11 + hh2*Wu12;
    constexpr float kL2E = 1.4426950408889634f;
    const float f0 = g0 * __builtin_amdgcn_rcpf(1.0f + __builtin_amdgcn_exp2f(-g0 * kL2E)) * u0;
    const float f1 = g1 * __builtin_amdgcn_rcpf(1.0f + __builtin_amdgcn_exp2f(-g1 * kL2E)) * u1;
    const float xf0 = xa0 + f0*Wd00 + f1*Wd01;
    const float xf1 = xa1 + f0*Wd10 + f1*Wd11;
    const float xf2 = xa2 + f0*Wd20 + f1*Wd21;

    // Final RMSNorm; only comps 0,1 feed the logits
    const float rf = __builtin_amdgcn_rsqf((xf0*xf0 + xf1*xf1 + xf2*xf2) * (1.0f/3.0f) + kEps);
    const float y0 = xf0 * rf * wlf0;
    const float y1 = xf1 * rf * wlf1;

    // Logits from the per-wave LDS table (uniform b128 broadcast reads;
    // ordering vs the table writes is covered by the fences above).
    const float4* tb4 = (const float4*)&tw[wid][0];
    const float4 T0 = tb4[0], T1 = tb4[1], T2 = tb4[2], T3 = tb4[3], T4 = tb4[4];

    // Stage this wave's 64x10 logits (2560 B, token-major contiguous) in LDS,
    // reusing the dead Vt buffer. Safe without an extra barrier: every staged
    // value depends transitively on all vb ds_reads (vb->acc->o->y0/y1), so
    // the ds_writes cannot issue before the reads completed.
    floatx2* F2 = (floatx2*)&smem[wid][0];         // 320 floatx2 = 2560 B
    F2[lane * 5 + 0] = floatx2{y0*T0.x + y1*T0.y, y0*T0.z + y1*T0.w};
    F2[lane * 5 + 1] = floatx2{y0*T1.x + y1*T1.y, y0*T1.z + y1*T1.w};
    F2[lane * 5 + 2] = floatx2{y0*T2.x + y1*T2.y, y0*T2.z + y1*T2.w};
    F2[lane * 5 + 3] = floatx2{y0*T3.x + y1*T3.y, y0*T3.z + y1*T3.w};
    F2[lane * 5 + 4] = floatx2{y0*T4.x + y1*T4.y, y0*T4.z + y1*T4.w};
    __threadfence_block();  // F2 writes -> cross-lane coalesced reads

    // Fully coalesced streaming stores: 2x dwordx4 + 1x dwordx2 per lane
    // (40 write segments/wave vs 200 with the old 40 B-stride pattern).
    const floatx4* F4 = (const floatx4*)F2;
    float* obase = out + (size_t)row * 640;
    __builtin_nontemporal_store(F4[lane],       (floatx4*)obase + lane);
    __builtin_nontemporal_store(F4[64 + lane],  (floatx4*)obase + 64 + lane);
    __builtin_nontemporal_store(F2[256 + lane], (floatx2*)obase + 256 + lane);
}
}  // namespace

extern "C" void kernel_launch(void* const* d_in, const int* in_sizes, int n_in,
                              void* d_out, int out_size, void* d_ws, size_t ws_size,
                              hipStream_t stream) {
    (void)in_sizes; (void)n_in; (void)d_ws; (void)ws_size; (void)out_size;
    const int*   idx       = (const int*)  d_in[0];
    const float* arcA      = (const float*)d_in[1];
    const float* arcStart  = (const float*)d_in[2];
    const float* arcStride = (const float*)d_in[3];
    const float* w_ln1     = (const float*)d_in[4];
    const float* w_ln2     = (const float*)d_in[5];
    const float* w_lnf     = (const float*)d_in[6];
    const float* w_qn      = (const float*)d_in[7];
    const float* Wq        = (const float*)d_in[8];
    const float* Wk        = (const float*)d_in[9];
    const float* Wg        = (const float*)d_in[10];
    const float* Wu        = (const float*)d_in[11];
    const float* Wd        = (const float*)d_in[12];
    float* out = (float*)d_out;

    dim3 grid(4096), block(256);   // 16384 waves = 1 row/wave, exact cover
    hipLaunchKernelGGL(adder_model_kernel, grid, block, 0, stream,
                       idx, arcA, arcStart, arcStride,
                       w_ln1, w_ln2, w_lnf, w_qn, Wq, Wk, Wg, Wu, Wd, out);
}

// Round 8
// 105.965 us; speedup vs baseline: 1.0114x; 1.0114x over previous
//
#include <hip/hip_runtime.h>
#include <math.h>

// AdderModel: B=16384 rows, T=64 (== wave), D=3, HD=4, FF=2, VOCAB=10.
// Round 18 = EXACT r12 restore (validated: passed at 106.1 us, absmax
// 0.03125). Zero experimental variables.
// Session knowledge encoded in this file (do not re-attempt):
//  - r13: QK^T k-slot MFMA fusion (3->1 per tile) degrades absmax
//    0.031->0.109. The 12-term single-MFMA reduction is numerically worse
//    than 3 chained 4-term MFMAs. KEEP the 3-MFMA hi/lo chains.
//  - r16/r17: computing the embedding per-lane from tix (instead of the
//    LDS table gather) fails absmax O(1) even on this exact base with
//    __syncthreads. "Same f32 expression" is NOT bit-identical across the
//    SALU-fed table path vs the VGPR per-lane path. KEEP the table gather.
//  - r15: 2-rows/wave restructure failed O(1), unexplained. Parked.
//  - r14's per-wave-table/fence-only variant passed once but its lineage
//    produced two unexplained failures; this block-table + __syncthreads
//    structure is the validated one.
// Structure: 1 row/wave, hi/lo fp32-accurate scores, cndmask-at-exp causal
// mask, half-up packs with exact split, register-order P + swap23 vcol,
// single Vt fence, LDS-staged fully-coalesced nontemporal stores.

namespace {
constexpr int kVocab = 10;
constexpr float kEps = 1e-6f;
constexpr int kWaves = 4;

typedef __attribute__((ext_vector_type(8)))  short short8;
typedef __attribute__((ext_vector_type(16))) float float16;
typedef __attribute__((ext_vector_type(4)))  float floatx4;
typedef __attribute__((ext_vector_type(2)))  float floatx2;

constexpr int kVtP = 72;          // Vt row pitch in shorts (144 B)
constexpr int kWaveLds = 2560;    // max(Vt 8x144 B, logit staging 64x40 B)

// f32 -> bf16, round-half-up (inputs finite; hi/lo split residual is taken
// from the ACTUAL packed hi, so the split stays exact).
__device__ __forceinline__ unsigned bf16_1(float a) {
    return (__float_as_uint(a) + 0x8000u) >> 16;
}
__device__ __forceinline__ unsigned pk_bf16(float a, float b) {
    const unsigned au = __float_as_uint(a) + 0x8000u;
    const unsigned bu = __float_as_uint(b) + 0x8000u;
    return (au >> 16) | (bu & 0xffff0000u);
}
__device__ __forceinline__ float bf_lo(unsigned u) { return __uint_as_float(u << 16); }
__device__ __forceinline__ float bf_hi(unsigned u) { return __uint_as_float(u & 0xffff0000u); }

__device__ __forceinline__ float16 mfma(short8 a, short8 b, float16 c) {
    return __builtin_amdgcn_mfma_f32_32x32x16_bf16(a, b, c, 0, 0, 0);
}
__device__ __forceinline__ unsigned shflx32(unsigned x) {
    return (unsigned)__shfl_xor((int)x, 32, 64);
}

// Frag from a packed bf16x4: k-slots 0..3 hold {x0..x3} on lanes<32 (k=0..7
// half), zeros on lanes>=32 (k=8..15 half).  [r8/r9-validated form]
__device__ __forceinline__ short8 mk_frag(uint2 v, bool lo) {
    uint4 t;
    t.x = lo ? v.x : 0u;
    t.y = lo ? v.y : 0u;
    t.z = 0u; t.w = 0u;
    return __builtin_bit_cast(short8, t);
}
__device__ __forceinline__ short8 ld8(const void* p) {
    return __builtin_bit_cast(short8, *(const uint4*)p);
}

// exp2 + pack a score tile IN REGISTER ORDER: out[i] = pk(e[2i], e[2i+1]).
// Causal mask (validated): reg r has s_local = (r&3)+8*(r>>2)+4h, keep iff
// ((r&3)+8*(r>>2)) <= m where m = tloc-4h.
template<bool MASKED>
__device__ __forceinline__ void exp_pack(const float16& S, unsigned* out, int m) {
#pragma unroll
    for (int i = 0; i < 8; ++i) {
        const int r0 = 2 * i, r1 = 2 * i + 1;
        float sa = S[r0], sb = S[r1];
        if (MASKED) {
            sa = (((r0 & 3) + 8 * (r0 >> 2)) <= m) ? sa : -INFINITY;  // exp2 -> 0
            sb = (((r1 & 3) + 8 * (r1 >> 2)) <= m) ? sb : -INFINITY;
        }
        out[i] = pk_bf16(__builtin_amdgcn_exp2f(sa), __builtin_amdgcn_exp2f(sb));
    }
}

// Operand chunk straight from 4 packed uints (8 bf16).
__device__ __forceinline__ short8 af(const unsigned* p) {
    uint4 t;
    t.x = p[0]; t.y = p[1]; t.z = p[2]; t.w = p[3];
    return __builtin_bit_cast(short8, t);
}

__global__ __launch_bounds__(256, 4) void adder_model_kernel(
    const int* __restrict__ idx,
    const float* __restrict__ p_arcA,
    const float* __restrict__ p_arcStart,
    const float* __restrict__ p_arcStride,
    const float* __restrict__ w_ln1,
    const float* __restrict__ w_ln2,
    const float* __restrict__ w_lnf,
    const float* __restrict__ w_qn,
    const float* __restrict__ Wq,
    const float* __restrict__ Wk,
    const float* __restrict__ Wg,
    const float* __restrict__ Wu,
    const float* __restrict__ Wd,
    float* __restrict__ out)
{
    __shared__ __align__(16) char smem[kWaves][kWaveLds];
    __shared__ __align__(16) float table_s[kVocab * 2];

    const int lane = threadIdx.x & 63;
    const int wid  = threadIdx.x >> 6;
    ushort* Vt = (ushort*)&smem[wid][0];

    if (threadIdx.x < kVocab) {
        const float ang = p_arcStart[0] + (float)threadIdx.x * p_arcStride[0];
        const float A = p_arcA[0];
        table_s[2 * threadIdx.x]     = A * __cosf(ang);
        table_s[2 * threadIdx.x + 1] = A * __sinf(ang);
    }
    __syncthreads();

    // Per-token constants
    const float t_f = (float)lane;
    const float pe  = __sinf(t_f * 1e-4f);
    const float c0  = __cosf(t_f);
    const float s0  = __sinf(t_f);
    const float ang1 = t_f * 0.57735026918962576f;
    const float c1  = __cosf(ang1);
    const float s1  = __sinf(ang1);

    // Scalar weight loads (uniform -> SGPR)
    const float wl1_0 = w_ln1[0], wl1_1 = w_ln1[1], wl1_2 = w_ln1[2];
    const float wl2_0 = w_ln2[0], wl2_1 = w_ln2[1], wl2_2 = w_ln2[2];
    const float wlf0 = w_lnf[0], wlf1 = w_lnf[1];
    const float wqn0 = w_qn[0], wqn1 = w_qn[1], wqn2 = w_qn[2], wqn3 = w_qn[3];
    const float Wq00 = Wq[0],  Wq01 = Wq[1],  Wq02 = Wq[2];
    const float Wq10 = Wq[3],  Wq11 = Wq[4],  Wq12 = Wq[5];
    const float Wq20 = Wq[6],  Wq21 = Wq[7],  Wq22 = Wq[8];
    const float Wq30 = Wq[9],  Wq31 = Wq[10], Wq32 = Wq[11];
    const float Wk00 = Wk[0],  Wk01 = Wk[1],  Wk02 = Wk[2];
    const float Wk10 = Wk[3],  Wk11 = Wk[4],  Wk12 = Wk[5];
    const float Wk20 = Wk[6],  Wk21 = Wk[7],  Wk22 = Wk[8];
    const float Wk30 = Wk[9],  Wk31 = Wk[10], Wk32 = Wk[11];
    const float Wg00 = Wg[0],  Wg01 = Wg[1],  Wg02 = Wg[2];
    const float Wg10 = Wg[3],  Wg11 = Wg[4],  Wg12 = Wg[5];
    const float Wu00 = Wu[0],  Wu01 = Wu[1],  Wu02 = Wu[2];
    const float Wu10 = Wu[3],  Wu11 = Wu[4],  Wu12 = Wu[5];
    const float Wd00 = Wd[0],  Wd01 = Wd[1];
    const float Wd10 = Wd[2],  Wd11 = Wd[3];
    const float Wd20 = Wd[4],  Wd21 = Wd[5];

    const int row = (int)blockIdx.x * kWaves + wid;

    const int tix = idx[(size_t)row * 64 + lane];
    const float2 emb = *(const float2*)(table_s + 2 * tix);
    const float x0i = emb.x, x1i = emb.y, x2i = pe;

    // RMSNorm 1 + projections
    const float r1 = __builtin_amdgcn_rsqf((x0i*x0i + x1i*x1i + x2i*x2i) * (1.0f/3.0f) + kEps);
    const float h0 = x0i * r1 * wl1_0;
    const float h1 = x1i * r1 * wl1_1;
    const float h2 = x2i * r1 * wl1_2;

    const float qp0 = h0*Wq00 + h1*Wq01 + h2*Wq02;
    const float qp1 = h0*Wq10 + h1*Wq11 + h2*Wq12;
    const float qp2 = h0*Wq20 + h1*Wq21 + h2*Wq22;
    const float qp3 = h0*Wq30 + h1*Wq31 + h2*Wq32;
    const float v0 = h0*Wk00 + h1*Wk01 + h2*Wk02;
    const float v1 = h0*Wk10 + h1*Wk11 + h2*Wk12;
    const float v2 = h0*Wk20 + h1*Wk21 + h2*Wk22;
    const float v3 = h0*Wk30 + h1*Wk31 + h2*Wk32;

    const float rq = __builtin_amdgcn_rsqf((qp0*qp0 + qp1*qp1 + qp2*qp2 + qp3*qp3) * 0.25f + kEps);
    const float rk = __builtin_amdgcn_rsqf((v0*v0 + v1*v1 + v2*v2 + v3*v3) * 0.25f + kEps);
    const float qn0 = qp0*rq*wqn0, qn1 = qp1*rq*wqn1, qn2 = qp2*rq*wqn2, qn3 = qp3*rq*wqn3;
    const float kn0 = v0*rk*wqn0,  kn1 = v1*rk*wqn1,  kn2 = v2*rk*wqn2,  kn3 = v3*rk*wqn3;

    // RoPE; fold 0.5*log2(e) into q -> scores land in exp2 domain
    constexpr float kQS = 0.72134752044448170f;
    const float q0 = (qn0*c0 - qn1*s0) * kQS;
    const float q1 = (qn0*s0 + qn1*c0) * kQS;
    const float q2 = (qn2*c1 - qn3*s1) * kQS;
    const float q3 = (qn2*s1 + qn3*c1) * kQS;
    const float k0 = kn0*c0 - kn1*s0;
    const float k1 = kn0*s0 + kn1*c0;
    const float k2 = kn2*c1 - kn3*s1;
    const float k3 = kn2*s1 + kn3*c1;

    // hi/lo bf16 split (residual from the ACTUAL packed hi -> exact split)
    uint2 qh, ql, kh, kl;
    qh.x = pk_bf16(q0, q1); qh.y = pk_bf16(q2, q3);
    ql.x = pk_bf16(q0 - bf_lo(qh.x), q1 - bf_hi(qh.x));
    ql.y = pk_bf16(q2 - bf_lo(qh.y), q3 - bf_hi(qh.y));
    kh.x = pk_bf16(k0, k1); kh.y = pk_bf16(k2, k3);
    kl.x = pk_bf16(k0 - bf_lo(kh.x), k1 - bf_hi(kh.x));
    kl.y = pk_bf16(k2 - bf_lo(kh.y), k3 - bf_hi(kh.y));

    // V' rows (d=0..3, ones row d=4, zero pad rows 5..7) at swap23 columns:
    // vcol(s) = swap(bit2,bit3)(s) matches the register k->s mapping
    // [0,1,2,3,8,9,10,11 | 4,5,6,7,12,13,14,15] per 16-chunk. [r9-validated]
    const int vcol = (lane & ~12) | ((lane & 4) << 1) | ((lane & 8) >> 1);
    Vt[0 * kVtP + vcol] = (ushort)bf16_1(v0);
    Vt[1 * kVtP + vcol] = (ushort)bf16_1(v1);
    Vt[2 * kVtP + vcol] = (ushort)bf16_1(v2);
    Vt[3 * kVtP + vcol] = (ushort)bf16_1(v3);
    Vt[4 * kVtP + vcol] = (ushort)0x3F80;  // bf16 1.0 -> l = sum_s P[t][s]
    Vt[5 * kVtP + vcol] = 0;               // defined junk for A pad rows
    Vt[6 * kVtP + vcol] = 0;
    Vt[7 * kVtP + vcol] = 0;

    // Tile-1 values: partner half's qh/ql/kh/kl via half-swap (no LDS buffer)
    uint2 qh1, ql1, kh1, kl1;
    qh1.x = shflx32(qh.x); qh1.y = shflx32(qh.y);
    ql1.x = shflx32(ql.x); ql1.y = shflx32(ql.y);
    kh1.x = shflx32(kh.x); kh1.y = shflx32(kh.y);
    kl1.x = shflx32(kl.x); kl1.y = shflx32(kl.y);

    const int  tloc = lane & 31;
    const bool loh  = lane < 32;
    const int  h    = lane >> 5;
    const int  m    = tloc - 4 * h;   // causal keep: s_local <= m

    // Fragments: tile-0 from own registers (lane<32 token == own lane;
    // lane>=32 zeroed by the select anyway). Tile-1 from the half-swap.
    const short8 aKh0 = mk_frag(kh,  loh);
    const short8 aKl0 = mk_frag(kl,  loh);
    const short8 aKh1 = mk_frag(kh1, loh);
    const short8 aKl1 = mk_frag(kl1, loh);
    const short8 bQh0 = mk_frag(qh,  loh);
    const short8 bQl0 = mk_frag(ql,  loh);
    const short8 bQh1 = mk_frag(qh1, loh);
    const short8 bQl1 = mk_frag(ql1, loh);

    __threadfence_block();  // Vt writes -> cross-lane vb reads

    // V' operand chunks (row d = tloc, pad-masked to 8 rows) [r9 read pattern]
    short8 vb[4];
#pragma unroll
    for (int kc = 0; kc < 4; ++kc)
        vb[kc] = ld8(Vt + (tloc & 7) * kVtP + 16 * kc + 8 * h);

    // S^T tiles = K.Q^T; 3-term hi/lo product (drop lo*lo ~2^-18)
    // [r12-validated numerics -- do NOT fuse into k-slot-packed MFMAs;
    //  r13 measured absmax 0.031 -> 0.109 from that fusion]
    float16 Z = {0,0,0,0,0,0,0,0,0,0,0,0,0,0,0,0};
    float16 S00 = mfma(aKl0, bQh0, mfma(aKh0, bQl0, mfma(aKh0, bQh0, Z)));
    float16 S01 = mfma(aKl0, bQh1, mfma(aKh0, bQl1, mfma(aKh0, bQh1, Z)));
    float16 S11 = mfma(aKl1, bQh1, mfma(aKh1, bQl1, mfma(aKh1, bQh1, Z)));

    // exp2 + pack in register order; packed regs ARE the PV B-operand.
    unsigned p00[8], p01[8], p11[8];
    exp_pack<true >(S00, p00, m);  // t<32,  s<32: diag mask
    exp_pack<false>(S01, p01, m);  // t>=32, s<32: fully kept
    exp_pack<true >(S11, p11, m);  // t>=32, s>=32: diag mask

    // O' = V'.P : A = vb (m=d), B = packed P (n=t) -> D[d][t] token-per-lane.
    float16 acc0 = mfma(vb[1], af(p00 + 4), mfma(vb[0], af(p00), Z));
    float16 acc1 = mfma(vb[3], af(p11 + 4),
                   mfma(vb[2], af(p11),
                   mfma(vb[1], af(p01 + 4),
                   mfma(vb[0], af(p01), Z))));

    // Redistribute via half-swap: lane(tloc,h=0) holds o0..3(tloc)=acc0[0..3]
    // and o0..3(tloc+32)=acc1[0..3]; lane(tloc,h=1) holds l(tloc)=acc0[0]
    // (m=4 -> r=0) and l(tloc+32)=acc1[0].
    const float e0 = __shfl_xor(loh ? acc1[0] : acc0[0], 32, 64);
    const float e1 = __shfl_xor(loh ? acc1[1] : acc0[1], 32, 64);
    const float e2 = __shfl_xor(loh ? acc1[2] : acc0[2], 32, 64);
    const float e3 = __shfl_xor(loh ? acc1[3] : acc0[3], 32, 64);
    const float o0r = loh ? acc0[0] : e0;
    const float o1r = loh ? acc0[1] : e1;
    const float o2r = loh ? acc0[2] : e2;
    const float o3r = loh ? acc0[3] : e3;
    const float lr  = loh ? e0 : acc1[0];

    const float invl = __builtin_amdgcn_rcpf(lr);
    const float o0 = o0r * invl, o1 = o1r * invl, o2 = o2r * invl, o3 = o3r * invl;

    // x += o @ Wq
    const float xa0 = x0i + o0*Wq00 + o1*Wq10 + o2*Wq20 + o3*Wq30;
    const float xa1 = x1i + o0*Wq01 + o1*Wq11 + o2*Wq21 + o3*Wq31;
    const float xa2 = x2i + o0*Wq02 + o1*Wq12 + o2*Wq22 + o3*Wq32;

    // MLP with RMSNorm 2
    const float r2 = __builtin_amdgcn_rsqf((xa0*xa0 + xa1*xa1 + xa2*xa2) * (1.0f/3.0f) + kEps);
    const float hh0 = xa0*r2*wl2_0, hh1 = xa1*r2*wl2_1, hh2 = xa2*r2*wl2_2;
    const float g0 = hh0*Wg00 + hh1*Wg01 + hh2*Wg02;
    const float g1 = hh0*Wg10 + hh1*Wg11 + hh2*Wg12;
    const float u0 = hh0*Wu00 + hh1*Wu01 + hh2*Wu02;
    const float u1 = hh0*Wu10 + hh1*Wu11 + hh2*Wu12;
    constexpr float kL2E = 1.4426950408889634f;
    const float f0 = g0 * __builtin_amdgcn_rcpf(1.0f + __builtin_amdgcn_exp2f(-g0 * kL2E)) * u0;
    const float f1 = g1 * __builtin_amdgcn_rcpf(1.0f + __builtin_amdgcn_exp2f(-g1 * kL2E)) * u1;
    const float xf0 = xa0 + f0*Wd00 + f1*Wd01;
    const float xf1 = xa1 + f0*Wd10 + f1*Wd11;
    const float xf2 = xa2 + f0*Wd20 + f1*Wd21;

    // Final RMSNorm; only comps 0,1 feed the logits
    const float rf = __builtin_amdgcn_rsqf((xf0*xf0 + xf1*xf1 + xf2*xf2) * (1.0f/3.0f) + kEps);
    const float y0 = xf0 * rf * wlf0;
    const float y1 = xf1 * rf * wlf1;

    // Logits from the LDS table (uniform b128 broadcast reads)
    const float4* tb4 = (const float4*)table_s;
    const float4 T0 = tb4[0], T1 = tb4[1], T2 = tb4[2], T3 = tb4[3], T4 = tb4[4];

    // Stage this wave's 64x10 logits (2560 B, token-major contiguous) in LDS,
    // reusing the dead Vt buffer. Safe without an extra barrier: every staged
    // value depends transitively on all vb ds_reads (vb->acc->o->y0/y1), so
    // the ds_writes cannot issue before the reads completed.
    floatx2* F2 = (floatx2*)&smem[wid][0];         // 320 floatx2 = 2560 B
    F2[lane * 5 + 0] = floatx2{y0*T0.x + y1*T0.y, y0*T0.z + y1*T0.w};
    F2[lane * 5 + 1] = floatx2{y0*T1.x + y1*T1.y, y0*T1.z + y1*T1.w};
    F2[lane * 5 + 2] = floatx2{y0*T2.x + y1*T2.y, y0*T2.z + y1*T2.w};
    F2[lane * 5 + 3] = floatx2{y0*T3.x + y1*T3.y, y0*T3.z + y1*T3.w};
    F2[lane * 5 + 4] = floatx2{y0*T4.x + y1*T4.y, y0*T4.z + y1*T4.w};
    __threadfence_block();  // F2 writes -> cross-lane coalesced reads

    // Fully coalesced streaming stores: 2x dwordx4 + 1x dwordx2 per lane
    // (40 write segments/wave vs 200 with the old 40 B-stride pattern).
    const floatx4* F4 = (const floatx4*)F2;
    float* obase = out + (size_t)row * 640;
    __builtin_nontemporal_store(F4[lane],       (floatx4*)obase + lane);
    __builtin_nontemporal_store(F4[64 + lane],  (floatx4*)obase + 64 + lane);
    __builtin_nontemporal_store(F2[256 + lane], (floatx2*)obase + 256 + lane);
}
}  // namespace

extern "C" void kernel_launch(void* const* d_in, const int* in_sizes, int n_in,
                              void* d_out, int out_size, void* d_ws, size_t ws_size,
                              hipStream_t stream) {
    (void)in_sizes; (void)n_in; (void)d_ws; (void)ws_size; (void)out_size;
    const int*   idx       = (const int*)  d_in[0];
    const float* arcA      = (const float*)d_in[1];
    const float* arcStart  = (const float*)d_in[2];
    const float* arcStride = (const float*)d_in[3];
    const float* w_ln1     = (const float*)d_in[4];
    const float* w_ln2     = (const float*)d_in[5];
    const float* w_lnf     = (const float*)d_in[6];
    const float* w_qn      = (const float*)d_in[7];
    const float* Wq        = (const float*)d_in[8];
    const float* Wk        = (const float*)d_in[9];
    const float* Wg        = (const float*)d_in[10];
    const float* Wu        = (const float*)d_in[11];
    const float* Wd        = (const float*)d_in[12];
    float* out = (float*)d_out;

    dim3 grid(4096), block(256);   // 16384 waves = 1 row/wave, exact cover
    hipLaunchKernelGGL(adder_model_kernel, grid, block, 0, stream,
                       idx, arcA, arcStart, arcStride,
                       w_ln1, w_ln2, w_lnf, w_qn, Wq, Wk, Wg, Wu, Wd, out);
}